// Round 20
// baseline (695.048 us; speedup 1.0000x reference)
//
#include <hip/hip_runtime.h>
#include <math.h>

constexpr int NN  = 30000;
constexpr int DIM = 128;
constexpr int KH  = 3;
constexpr int NC  = 6;
constexpr int EE  = 480000;
constexpr int NBLK3 = (3 * NN + 255) / 256;   // 352 scan blocks (batched)

typedef __attribute__((ext_vector_type(8))) short short8;
typedef __attribute__((ext_vector_type(4))) float f32x4;
typedef __attribute__((ext_vector_type(2))) float f32x2;
typedef __attribute__((ext_vector_type(4))) unsigned int u32x4;

__device__ __forceinline__ unsigned short f2bf(float f) {
    union { float f; unsigned int i; } c; c.f = f;
    unsigned int u = c.i;
    return (unsigned short)((u + 0x7fffu + ((u >> 16) & 1u)) >> 16);
}
__device__ __forceinline__ float bf2f(unsigned int u) {
    union { unsigned int i; float f; } c; c.i = u << 16; return c.f;
}
__device__ __forceinline__ unsigned int packbf(float x, float y) {
    return (unsigned int)f2bf(x) | ((unsigned int)f2bf(y) << 16);
}
__device__ __forceinline__ float fsig(float x) {
    return __builtin_amdgcn_rcpf(1.f + __expf(-x));
}
__device__ __forceinline__ float ftanh(float x) {
    return 2.f * fsig(2.f * x) - 1.f;
}
// 4 fp8 (one u32) -> 2 u32 of bf16 pairs
__device__ __forceinline__ void fp8x4_to_bf16x4(unsigned int x,
                                                unsigned int& o0, unsigned int& o1)
{
    f32x2 lo = __builtin_amdgcn_cvt_pk_f32_fp8(x, false);
    f32x2 hi = __builtin_amdgcn_cvt_pk_f32_fp8(x, true);
    o0 = packbf(lo.x, lo.y);
    o1 = packbf(hi.x, hi.y);
}

// ---------------------------------------------------------------------------
// bf16 MFMA GEMM (reg-staged). A split at ksplit (A1 bf16 / A2 bf16-or-fp8).
// A2FP8: A2 is fp8 e4m3 (lda2 in BYTES per row); converted to bf16 at staging.
// OUT: 0 = bf16 C, 1 = fp8 C. XCD-chunked bijective swizzle.
// ---------------------------------------------------------------------------
template<int OUT, bool RELU, bool A2FP8>
__global__ __launch_bounds__(256) void mgemm(
    const unsigned short* __restrict__ A1, int lda1,
    const void* __restrict__ A2, int lda2, int ksplit,
    const unsigned short* __restrict__ Bt, int ldb,
    const float* __restrict__ bias,
    void* __restrict__ Cv, int ldc,
    int M, int K, int nx)
{
    __shared__ __align__(16) unsigned char smem[2 * 128 * 80];
    unsigned char* As = smem;
    unsigned char* Bs = smem + 128 * 80;

    const int nwg  = gridDim.x;
    const int orig = blockIdx.x;
    const int q = nwg >> 3, r = nwg & 7;
    const int xcd = orig & 7, idx = orig >> 3;
    const int lin = (xcd < r ? xcd * (q + 1) : r * (q + 1) + (xcd - r) * q) + idx;
    const int bx = lin % nx, by = lin / nx;

    const int tid  = threadIdx.x;
    const int lane = tid & 63;
    const int w    = tid >> 6;
    const int wm   = w >> 1, wn = w & 1;
    const int lm   = lane & 15, lg = lane >> 4;
    const int bm   = by * 128;
    const int bn   = bx * 128;

    const int srow  = tid >> 1;
    const int shalf = tid & 1;

    f32x4 acc[4][4] = {};

    int arow = bm + srow; if (arow > M - 1) arow = M - 1;
    const int brow = bn + srow;

    for (int k0 = 0; k0 < K; k0 += 32) {
        float4 a0, a1;
        if (k0 < ksplit) {
            const float4* ga = (const float4*)(A1 + (size_t)arow * lda1 + k0 + shalf * 16);
            a0 = ga[0]; a1 = ga[1];
        } else if (!A2FP8) {
            const unsigned short* Ap = (const unsigned short*)A2;
            const float4* ga = (const float4*)(Ap + (size_t)arow * lda2 + (k0 - ksplit) + shalf * 16);
            a0 = ga[0]; a1 = ga[1];
        } else {
            const unsigned char* gp = (const unsigned char*)A2 +
                (size_t)arow * lda2 + (k0 - ksplit) + shalf * 16;
            uint4 v = *(const uint4*)gp;
            unsigned int o[8];
            fp8x4_to_bf16x4(v.x, o[0], o[1]);
            fp8x4_to_bf16x4(v.y, o[2], o[3]);
            fp8x4_to_bf16x4(v.z, o[4], o[5]);
            fp8x4_to_bf16x4(v.w, o[6], o[7]);
            a0 = *(float4*)&o[0];
            a1 = *(float4*)&o[4];
        }
        const float4* gb = (const float4*)(Bt + (size_t)brow * ldb + k0 + shalf * 16);
        float4 b0 = gb[0], b1 = gb[1];

        __syncthreads();
        *(float4*)(As + srow * 80 + shalf * 32)      = a0;
        *(float4*)(As + srow * 80 + shalf * 32 + 16) = a1;
        *(float4*)(Bs + srow * 80 + shalf * 32)      = b0;
        *(float4*)(Bs + srow * 80 + shalf * 32 + 16) = b1;
        __syncthreads();

        short8 av[4], bv[4];
        #pragma unroll
        for (int f = 0; f < 4; ++f) {
            av[f] = *(const short8*)(As + (wm * 64 + f * 16 + lm) * 80 + lg * 16);
            bv[f] = *(const short8*)(Bs + (wn * 64 + f * 16 + lm) * 80 + lg * 16);
        }
        #pragma unroll
        for (int i = 0; i < 4; ++i)
            #pragma unroll
            for (int j = 0; j < 4; ++j)
                acc[i][j] = __builtin_amdgcn_mfma_f32_16x16x32_bf16(
                    av[i], bv[j], acc[i][j], 0, 0, 0);
    }

    #pragma unroll
    for (int i = 0; i < 4; ++i) {
        int row0 = bm + wm * 64 + i * 16 + lg * 4;
        #pragma unroll
        for (int j = 0; j < 4; ++j) {
            int col = bn + wn * 64 + j * 16 + lm;
            float bb = bias[col];
            #pragma unroll
            for (int r2 = 0; r2 < 4; ++r2) {
                int row = row0 + r2;
                if (row < M) {
                    float v = acc[i][j][r2] + bb;
                    if (RELU) v = fmaxf(v, 0.f);
                    if (OUT == 0) {
                        ((unsigned short*)Cv)[(size_t)row * ldc + col] = f2bf(v);
                    } else {
                        unsigned int pk = __builtin_amdgcn_cvt_pk_fp8_f32(v, v, 0, false);
                        ((unsigned char*)Cv)[(size_t)row * ldc + col] = (unsigned char)pk;
                    }
                }
            }
        }
    }
}

// ---------------------------------------------------------------------------
// Batched CSR build; edge record = 16B {src, 6 bf16 w}; off values GLOBAL.
// Streaming loads/stores marked non-temporal to spare L2 for reused data.
// ---------------------------------------------------------------------------
__global__ void hist3(const int* __restrict__ EL, int* __restrict__ cnt)
{
    int t = blockIdx.x * 256 + threadIdx.x;
    int e0 = t * 4;
    if (e0 >= 3 * EE) return;
    int g = e0 / EE;
    int e = e0 - g * EE;
    u32x4 d4 = __builtin_nontemporal_load(
        (const u32x4*)(EL + (size_t)g * 2 * EE + EE + e));
    int* c = cnt + g * NN;
    atomicAdd(&c[(int)d4[0]], 1);
    atomicAdd(&c[(int)d4[1]], 1);
    atomicAdd(&c[(int)d4[2]], 1);
    atomicAdd(&c[(int)d4[3]], 1);
}

__global__ __launch_bounds__(256) void scan_part(const int* __restrict__ cnt,
                                                 int* __restrict__ off,
                                                 int* __restrict__ bsum, int n)
{
    int lane = threadIdx.x & 63, wid = threadIdx.x >> 6;
    int i = blockIdx.x * 256 + threadIdx.x;
    int v = (i < n) ? cnt[i] : 0;
    int x = v;
    #pragma unroll
    for (int ofs = 1; ofs < 64; ofs <<= 1) {
        int t = __shfl_up(x, ofs, 64);
        if (lane >= ofs) x += t;
    }
    __shared__ int ws[4];
    if (lane == 63) ws[wid] = x;
    __syncthreads();
    int wo = 0;
    for (int j = 0; j < wid; ++j) wo += ws[j];
    if (i < n) off[i] = wo + x - v;
    if (threadIdx.x == 255) bsum[blockIdx.x] = wo + x;
}

__global__ __launch_bounds__(512) void scan_tops(const int* __restrict__ bsum,
                                                 int* __restrict__ btop, int nb)
{
    __shared__ int buf[512];
    int v = (threadIdx.x < nb) ? bsum[threadIdx.x] : 0;
    buf[threadIdx.x] = v;
    __syncthreads();
    #pragma unroll
    for (int ofs = 1; ofs < 512; ofs <<= 1) {
        int t = (threadIdx.x >= ofs) ? buf[threadIdx.x - ofs] : 0;
        __syncthreads();
        buf[threadIdx.x] += t;
        __syncthreads();
    }
    if (threadIdx.x < nb) btop[threadIdx.x] = buf[threadIdx.x] - v;
}

__global__ __launch_bounds__(256) void scan_add(int* __restrict__ off,
                                                const int* __restrict__ btop,
                                                int* __restrict__ cursor,
                                                int n, int etot)
{
    int i = blockIdx.x * 256 + threadIdx.x;
    if (i < n) {
        int o = off[i] + btop[blockIdx.x];
        off[i] = o;
        cursor[i] = o;
    }
    if (blockIdx.x == 0 && threadIdx.x == 0) off[n] = etot;
}

__global__ void fill3(const int* __restrict__ EL, const float* __restrict__ SW,
                      int* __restrict__ cursor, unsigned int* __restrict__ rec)
{
    int t = blockIdx.x * 256 + threadIdx.x;
    int e0 = t * 4;
    if (e0 >= 3 * EE) return;
    int g = e0 / EE;
    int e = e0 - g * EE;
    const int* base = EL + (size_t)g * 2 * EE;
    u32x4 s4 = __builtin_nontemporal_load((const u32x4*)(base + e));
    u32x4 d4 = __builtin_nontemporal_load((const u32x4*)(base + EE + e));
    const float* sw = SW + (size_t)g * NC * EE;
    f32x4 w0 = __builtin_nontemporal_load((const f32x4*)(sw + e));
    f32x4 w1 = __builtin_nontemporal_load((const f32x4*)(sw + (size_t)EE + e));
    f32x4 w2 = __builtin_nontemporal_load((const f32x4*)(sw + 2 * (size_t)EE + e));
    f32x4 w3 = __builtin_nontemporal_load((const f32x4*)(sw + 3 * (size_t)EE + e));
    f32x4 w4 = __builtin_nontemporal_load((const f32x4*)(sw + 4 * (size_t)EE + e));
    f32x4 w5 = __builtin_nontemporal_load((const f32x4*)(sw + 5 * (size_t)EE + e));
    int* cur = cursor + g * NN;
    int p0 = atomicAdd(&cur[(int)d4[0]], 1);
    int p1 = atomicAdd(&cur[(int)d4[1]], 1);
    int p2 = atomicAdd(&cur[(int)d4[2]], 1);
    int p3 = atomicAdd(&cur[(int)d4[3]], 1);
    u32x4 r0 = { s4[0], packbf(w0.x, w1.x), packbf(w2.x, w3.x), packbf(w4.x, w5.x) };
    u32x4 r1 = { s4[1], packbf(w0.y, w1.y), packbf(w2.y, w3.y), packbf(w4.y, w5.y) };
    u32x4 r2 = { s4[2], packbf(w0.z, w1.z), packbf(w2.z, w3.z), packbf(w4.z, w5.z) };
    u32x4 r3 = { s4[3], packbf(w0.w, w1.w), packbf(w2.w, w3.w), packbf(w4.w, w5.w) };
    __builtin_nontemporal_store(r0, (u32x4*)(rec + (size_t)p0 * 4));
    __builtin_nontemporal_store(r1, (u32x4*)(rec + (size_t)p1 * 4));
    __builtin_nontemporal_store(r2, (u32x4*)(rec + (size_t)p2 * 4));
    __builtin_nontemporal_store(r3, (u32x4*)(rec + (size_t)p3 * 4));
}

// ---------------------------------------------------------------------------
// Fused 6-conv weighted segment-mean gather over 16B edge records.
// 2 waves/node, unroll-4. rec loads + agg stores non-temporal (streaming);
// h8 rows (reused ~16x) keep L2 residency. agg fp8 [*,768].
// ---------------------------------------------------------------------------
__device__ __forceinline__ void wunpack(u32x4 r, int half,
                                        float& w0, float& w1, float& w2)
{
    if (half == 0) {
        w0 = bf2f(r[1] & 0xffffu); w1 = bf2f(r[1] >> 16); w2 = bf2f(r[2] & 0xffffu);
    } else {
        w0 = bf2f(r[2] >> 16); w1 = bf2f(r[3] & 0xffffu); w2 = bf2f(r[3] >> 16);
    }
}

__global__ __launch_bounds__(256) void gather6(
    const unsigned char* __restrict__ h8,
    const unsigned int* __restrict__ rec,   // 4 u32 per edge
    const int* __restrict__ off,
    unsigned char* __restrict__ agg,        // fp8 [*,768]
    int nnodes)
{
    int wid  = threadIdx.x >> 6;
    int lane = threadIdx.x & 63;
    int node = blockIdx.x * 2 + (wid >> 1);
    int half = wid & 1;
    if (node >= nnodes) return;
    int rowbase = (node / NN) * NN;
    int s0 = off[node], s1 = off[node + 1];
    float a0 = 0.f, a1 = 0.f, b0 = 0.f, b1 = 0.f, c0 = 0.f, c1 = 0.f;
    const size_t hofs = (size_t)half * 384 + (size_t)lane * 2;
    const unsigned char* hb = h8 + (size_t)rowbase * 768 + hofs;

    int e = s0;
    for (; e + 3 < s1; e += 4) {
        u32x4 rA = __builtin_nontemporal_load((const u32x4*)(rec + (size_t)e * 4));
        u32x4 rB = __builtin_nontemporal_load((const u32x4*)(rec + (size_t)(e + 1) * 4));
        u32x4 rC = __builtin_nontemporal_load((const u32x4*)(rec + (size_t)(e + 2) * 4));
        u32x4 rD = __builtin_nontemporal_load((const u32x4*)(rec + (size_t)(e + 3) * 4));
        const unsigned short* pA = (const unsigned short*)(hb + (size_t)rA[0] * 768);
        const unsigned short* pB = (const unsigned short*)(hb + (size_t)rB[0] * 768);
        const unsigned short* pC = (const unsigned short*)(hb + (size_t)rC[0] * 768);
        const unsigned short* pD = (const unsigned short*)(hb + (size_t)rD[0] * 768);
        unsigned int pA0 = pA[0], pA1 = pA[64], pA2 = pA[128];
        unsigned int pB0 = pB[0], pB1 = pB[64], pB2 = pB[128];
        unsigned int pC0 = pC[0], pC1 = pC[64], pC2 = pC[128];
        unsigned int pD0 = pD[0], pD1 = pD[64], pD2 = pD[128];

        float w0, w1, w2;
        wunpack(rA, half, w0, w1, w2);
        {
            f32x2 h0 = __builtin_amdgcn_cvt_pk_f32_fp8(pA0, false);
            f32x2 h1 = __builtin_amdgcn_cvt_pk_f32_fp8(pA1, false);
            f32x2 h2 = __builtin_amdgcn_cvt_pk_f32_fp8(pA2, false);
            a0 += w0 * h0.x; a1 += w0 * h0.y;
            b0 += w1 * h1.x; b1 += w1 * h1.y;
            c0 += w2 * h2.x; c1 += w2 * h2.y;
        }
        wunpack(rB, half, w0, w1, w2);
        {
            f32x2 h0 = __builtin_amdgcn_cvt_pk_f32_fp8(pB0, false);
            f32x2 h1 = __builtin_amdgcn_cvt_pk_f32_fp8(pB1, false);
            f32x2 h2 = __builtin_amdgcn_cvt_pk_f32_fp8(pB2, false);
            a0 += w0 * h0.x; a1 += w0 * h0.y;
            b0 += w1 * h1.x; b1 += w1 * h1.y;
            c0 += w2 * h2.x; c1 += w2 * h2.y;
        }
        wunpack(rC, half, w0, w1, w2);
        {
            f32x2 h0 = __builtin_amdgcn_cvt_pk_f32_fp8(pC0, false);
            f32x2 h1 = __builtin_amdgcn_cvt_pk_f32_fp8(pC1, false);
            f32x2 h2 = __builtin_amdgcn_cvt_pk_f32_fp8(pC2, false);
            a0 += w0 * h0.x; a1 += w0 * h0.y;
            b0 += w1 * h1.x; b1 += w1 * h1.y;
            c0 += w2 * h2.x; c1 += w2 * h2.y;
        }
        wunpack(rD, half, w0, w1, w2);
        {
            f32x2 h0 = __builtin_amdgcn_cvt_pk_f32_fp8(pD0, false);
            f32x2 h1 = __builtin_amdgcn_cvt_pk_f32_fp8(pD1, false);
            f32x2 h2 = __builtin_amdgcn_cvt_pk_f32_fp8(pD2, false);
            a0 += w0 * h0.x; a1 += w0 * h0.y;
            b0 += w1 * h1.x; b1 += w1 * h1.y;
            c0 += w2 * h2.x; c1 += w2 * h2.y;
        }
    }
    for (; e < s1; ++e) {
        u32x4 r = __builtin_nontemporal_load((const u32x4*)(rec + (size_t)e * 4));
        float w0, w1, w2;
        wunpack(r, half, w0, w1, w2);
        const unsigned short* hrow = (const unsigned short*)(hb + (size_t)r[0] * 768);
        unsigned int q0 = hrow[0];
        unsigned int q1 = hrow[64];
        unsigned int q2 = hrow[128];
        f32x2 h0 = __builtin_amdgcn_cvt_pk_f32_fp8(q0, false);
        f32x2 h1 = __builtin_amdgcn_cvt_pk_f32_fp8(q1, false);
        f32x2 h2 = __builtin_amdgcn_cvt_pk_f32_fp8(q2, false);
        a0 += w0 * h0.x; a1 += w0 * h0.y;
        b0 += w1 * h1.x; b1 += w1 * h1.y;
        c0 += w2 * h2.x; c1 += w2 * h2.y;
    }
    float inv = 1.f / fmaxf((float)(s1 - s0), 1.f);
    unsigned short* orow = (unsigned short*)(agg + (size_t)node * 768) + 192 * half + lane;
    __builtin_nontemporal_store(
        (unsigned short)__builtin_amdgcn_cvt_pk_fp8_f32(a0 * inv, a1 * inv, 0, false), orow);
    __builtin_nontemporal_store(
        (unsigned short)__builtin_amdgcn_cvt_pk_fp8_f32(b0 * inv, b1 * inv, 0, false), orow + 64);
    __builtin_nontemporal_store(
        (unsigned short)__builtin_amdgcn_cvt_pk_fp8_f32(c0 * inv, c1 * inv, 0, false), orow + 128);
}

// ---------------------------------------------------------------------------
__global__ void cvt_h(const float* __restrict__ Hk, unsigned int* __restrict__ out,
                      int total)
{
    int idx = blockIdx.x * 256 + threadIdx.x;
    if (idx >= total) return;
    float2 v = ((const float2*)Hk)[idx];
    out[idx] = packbf(v.x, v.y);
}

// ---------------------------------------------------------------------------
// Fused 3-step LSTM (weights hoisted to registers; unchanged).
// ---------------------------------------------------------------------------
#define SWA32(r, b) ((r) * 512 + ((b) ^ (((r) & 7) << 4)))

__global__ __launch_bounds__(512) void lstm_fused(
    const unsigned short* __restrict__ xs,   // [3][NN][128]
    const unsigned short* __restrict__ Wt,   // [512][256] permuted rows
    const float* __restrict__ bsum,          // [512] permuted
    float* __restrict__ outp)                // [NN][128]
{
    __shared__ __align__(16) unsigned char AL[32 * 512];

    const int tid  = threadIdx.x;
    const int lane = tid & 63;
    const int w    = tid >> 6;              // 0..7
    const int lm   = lane & 15, lg = lane >> 4;
    const int node0 = blockIdx.x * 32;

    float bias[4];
    #pragma unroll
    for (int g = 0; g < 4; ++g)
        bias[g] = bsum[w * 64 + g * 16 + lm];

    short8 bw[8][4];
    #pragma unroll
    for (int ks = 0; ks < 8; ++ks)
        #pragma unroll
        for (int g = 0; g < 4; ++g)
            bw[ks][g] = *(const short8*)(Wt +
                (size_t)(w * 64 + g * 16 + lm) * 256 + ks * 32 + lg * 8);

    float cst[2][4] = {};

    float4 z4 = make_float4(0.f, 0.f, 0.f, 0.f);
    {
        int r = tid >> 4, gi = tid & 15;
        *(float4*)(AL + SWA32(r, 256 + gi * 16)) = z4;
    }

    for (int t = 0; t < KH; ++t) {
        const unsigned short* xsrc = xs + (size_t)t * NN * 128;
        {
            int r = tid >> 4, gi = tid & 15;
            int gr = node0 + r; if (gr >= NN) gr = NN - 1;
            float4 v = *(const float4*)(xsrc + (size_t)gr * 128 + gi * 8);
            *(float4*)(AL + SWA32(r, gi * 16)) = v;
        }
        __syncthreads();

        f32x4 acc[2][4] = {};
        #pragma unroll
        for (int ks = 0; ks < 8; ++ks) {
            short8 av[2];
            #pragma unroll
            for (int i = 0; i < 2; ++i)
                av[i] = *(const short8*)(AL + SWA32(i * 16 + lm, ks * 64 + lg * 16));
            #pragma unroll
            for (int g = 0; g < 4; ++g)
                #pragma unroll
                for (int i = 0; i < 2; ++i)
                    acc[i][g] = __builtin_amdgcn_mfma_f32_16x16x32_bf16(
                        av[i], bw[ks][g], acc[i][g], 0, 0, 0);
        }
        __syncthreads();

        #pragma unroll
        for (int i = 0; i < 2; ++i)
            #pragma unroll
            for (int r = 0; r < 4; ++r) {
                float giv = acc[i][0][r] + bias[0];
                float gfv = acc[i][1][r] + bias[1];
                float ggv = acc[i][2][r] + bias[2];
                float gov = acc[i][3][r] + bias[3];
                float si = fsig(giv);
                float sf = fsig(gfv);
                float so = fsig(gov);
                float cv = sf * cst[i][r] + si * ftanh(ggv);
                cst[i][r] = cv;
                float hv = so * ftanh(cv);
                int row = i * 16 + lg * 4 + r;
                int d   = w * 16 + lm;
                if (t < KH - 1) {
                    *(unsigned short*)(AL + SWA32(row, 256 + 2 * d)) = f2bf(hv);
                } else if (node0 + row < NN) {
                    outp[(size_t)(node0 + row) * 128 + d] = fmaxf(hv, 0.f);
                }
            }
    }
}

// ---------------------------------------------------------------------------
// Weight precompute: tiled fp32 GEMM fold (unchanged).
// ---------------------------------------------------------------------------
__global__ __launch_bounds__(256) void wt_fold(
    const float* __restrict__ Wcomb,
    const float* __restrict__ Wroot,
    const float* __restrict__ Wrel,
    unsigned short* __restrict__ Wfull_t)
{
    __shared__ __align__(16) float As[16][68];
    __shared__ __align__(16) float Bs[16][68];
    const int tid = threadIdx.x;
    const int tx = tid & 15, ty = tid >> 4;
    const int bm = blockIdx.y * 64;
    const int bn = blockIdx.x * 64;
    const bool root = (bm < 128);
    const int i0 = root ? 0 : (bm >> 7) - 1;
    const int i1 = root ? NC : i0 + 1;
    const int mloc = bm & 127;
    const int a_m = tid >> 2, a_k = (tid & 3) * 4;
    const int b_k = tid >> 4, b_n = (tid & 15) * 4;

    float acc[4][4] = {};

    for (int i = i0; i < i1; ++i) {
        const float* A = (root ? Wroot : Wrel) + (size_t)i * 128 * 128;
        const float* B = Wcomb + (size_t)(i + 1) * 128 * 384;
        for (int k0 = 0; k0 < 128; k0 += 16) {
            float4 va = *(const float4*)(A + (size_t)(mloc + a_m) * 128 + k0 + a_k);
            float4 vb = *(const float4*)(B + (size_t)(k0 + b_k) * 384 + bn + b_n);
            __syncthreads();
            As[a_k + 0][a_m] = va.x; As[a_k + 1][a_m] = va.y;
            As[a_k + 2][a_m] = va.z; As[a_k + 3][a_m] = va.w;
            *(float4*)&Bs[b_k][b_n] = vb;
            __syncthreads();
            #pragma unroll
            for (int kk = 0; kk < 16; ++kk) {
                float4 av = *(const float4*)&As[kk][ty * 4];
                float4 bv = *(const float4*)&Bs[kk][tx * 4];
                float a[4] = {av.x, av.y, av.z, av.w};
                float b[4] = {bv.x, bv.y, bv.z, bv.w};
                #pragma unroll
                for (int ii = 0; ii < 4; ++ii)
                    #pragma unroll
                    for (int j = 0; j < 4; ++j)
                        acc[ii][j] += a[ii] * b[j];
            }
        }
    }

    #pragma unroll
    for (int ii = 0; ii < 4; ++ii) {
        int m = bm + ty * 4 + ii;
        #pragma unroll
        for (int j = 0; j < 4; ++j) {
            int n = bn + tx * 4 + j;
            float v = acc[ii][j];
            if (root) v += Wcomb[(size_t)m * 384 + n];
            Wfull_t[(size_t)n * 896 + m] = f2bf(v);
        }
    }
}

// ---------------------------------------------------------------------------
__global__ __launch_bounds__(256) void tr_cvt(
    const float* __restrict__ src, unsigned short* __restrict__ dst,
    int R, int C)
{
    __shared__ float s[32][33];
    const float* sb = src + (size_t)blockIdx.z * R * C;
    unsigned short* db = dst + (size_t)blockIdx.z * R * C;
    int r0 = blockIdx.y * 32, c0 = blockIdx.x * 32;
    int tx = threadIdx.x & 31, ty = threadIdx.x >> 5;   // 32x8
    #pragma unroll
    for (int q = 0; q < 4; ++q)
        s[ty + q * 8][tx] = sb[(size_t)(r0 + ty + q * 8) * C + c0 + tx];
    __syncthreads();
    #pragma unroll
    for (int q = 0; q < 4; ++q)
        db[(size_t)(c0 + ty + q * 8) * R + r0 + tx] = f2bf(s[tx][ty + q * 8]);
}

__global__ void wt_lstm(const float* __restrict__ Wih, const float* __restrict__ Whh,
                        const float* __restrict__ bih, const float* __restrict__ bhh,
                        unsigned short* __restrict__ Wt, float* __restrict__ bsum)
{
    int idx = blockIdx.x * 256 + threadIdx.x;
    if (idx < 512) {
        int w = idx >> 6, rem = idx & 63, g = rem >> 4, d16 = rem & 15;
        int n = g * 128 + w * 16 + d16;
        bsum[idx] = bih[n] + bhh[n];
    }
    if (idx >= 512 * 256) return;
    int k = idx & 255, np = idx >> 8;
    int w = np >> 6, rem = np & 63, g = rem >> 4, d16 = rem & 15;
    int n = g * 128 + w * 16 + d16;
    Wt[idx] = f2bf(k < 128 ? Wih[(size_t)n * DIM + k]
                           : Whh[(size_t)n * DIM + (k - 128)]);
}

// ---------------------------------------------------------------------------
extern "C" void kernel_launch(void* const* d_in, const int* in_sizes, int n_in,
                              void* d_out, int out_size, void* d_ws, size_t ws_size,
                              hipStream_t stream)
{
    const float* H     = (const float*)d_in[0];
    const int*   EL    = (const int*)  d_in[1];
    const float* SW    = (const float*)d_in[2];
    const float* Wp    = (const float*)d_in[3];
    const float* bp    = (const float*)d_in[4];
    const float* Wrel  = (const float*)d_in[5];
    const float* Wroot = (const float*)d_in[6];
    const float* Wcomb = (const float*)d_in[7];
    const float* bcomb = (const float*)d_in[8];
    const float* Wpl   = (const float*)d_in[9];
    const float* bpl   = (const float*)d_in[10];
    const float* Wih   = (const float*)d_in[11];
    const float* Whh   = (const float*)d_in[12];
    const float* bih   = (const float*)d_in[13];
    const float* bhh   = (const float*)d_in[14];

    char* wp = (char*)d_ws;
    auto alloc = [&](size_t b) {
        char* p = wp; wp += (b + 255) & ~(size_t)255; return p;
    };

    // common allocations (~71 MB)
    unsigned short* Hbf  = (unsigned short*)alloc((size_t)3 * NN * 128 * 2);
    unsigned short* xs   = (unsigned short*)alloc((size_t)KH * NN * 128 * 2);
    unsigned int* rec = (unsigned int*)alloc((size_t)3 * EE * 16);
    int* cnt     = (int*)alloc((size_t)3 * NN * 4);
    int* off     = (int*)alloc((size_t)(3 * NN + 1) * 4);
    int* cursor  = (int*)alloc((size_t)3 * NN * 4);
    int* bsum    = (int*)alloc((size_t)NBLK3 * 4);
    int* btop    = (int*)alloc((size_t)NBLK3 * 4);
    unsigned short* Wp_t     = (unsigned short*)alloc((size_t)768 * 128 * 2);
    unsigned short* Wfull_t  = (unsigned short*)alloc((size_t)384 * 896 * 2);
    unsigned short* Wpl_t    = (unsigned short*)alloc((size_t)128 * 512 * 2);
    unsigned short* WihWhh_t = (unsigned short*)alloc((size_t)512 * 256 * 2);
    float* bias_lstm         = (float*)alloc(512 * 4);

    // chunked buffers: proj ALIASES h8 (identical byte size; hazard-free).
    size_t used = (size_t)(wp - (char*)d_ws);
    size_t per_graph = (size_t)NN * 768 * 2 + 1024;
    const int nb = (ws_size - used >= 3 * per_graph + 4096) ? 1 : 3;  // 1 => batched
    const int GM = (nb == 1) ? 3 : 1;
    unsigned char*  h8   = (unsigned char*) alloc((size_t)GM * NN * 768);
    unsigned char*  agg8 = (unsigned char*) alloc((size_t)GM * NN * 768);
    unsigned short* proj = (unsigned short*)h8;   // alias (GM*NN*384*2 == GM*NN*768)

    // ---- weight precompute ----
    tr_cvt<<<dim3(4, 4, 6), 256, 0, stream>>>(Wp, Wp_t, 128, 128);
    wt_fold<<<dim3(6, 14), 256, 0, stream>>>(Wcomb, Wroot, Wrel, Wfull_t);
    tr_cvt<<<dim3(4, 16, 1), 256, 0, stream>>>(Wpl, Wpl_t, 512, 128);
    wt_lstm<<<(512 * 256 + 255) / 256, 256, 0, stream>>>(Wih, Whh, bih, bhh,
                                                         WihWhh_t, bias_lstm);

    // ---- batched CSR build (ILP-4 direct scatter, nt streams) ----
    hipMemsetAsync(cnt, 0, (size_t)3 * NN * 4, stream);
    hist3<<<(3 * EE / 4 + 255) / 256, 256, 0, stream>>>(EL, cnt);
    scan_part<<<NBLK3, 256, 0, stream>>>(cnt, off, bsum, 3 * NN);
    scan_tops<<<1, 512, 0, stream>>>(bsum, btop, NBLK3);
    scan_add<<<NBLK3, 256, 0, stream>>>(off, btop, cursor, 3 * NN, 3 * EE);
    fill3<<<(3 * EE / 4 + 255) / 256, 256, 0, stream>>>(EL, SW, cursor, rec);

    // ---- batched fp32->bf16 convert of all H ----
    cvt_h<<<(3 * NN * 64 + 255) / 256, 256, 0, stream>>>(H, (unsigned int*)Hbf,
                                                         3 * NN * 64);

    const int CM = GM * NN;
    const int MB = (CM + 127) / 128;

    for (int c = 0; c < nb; ++c) {
        const int rows0 = c * NN;
        const unsigned short* Hbk = Hbf + (size_t)rows0 * 128;

        // h8 = fp8(relu(Hbk @ Wp_all + bp))   [CM,768]
        mgemm<1, true, false><<<6 * MB, 256, 0, stream>>>(
            Hbk, 128, (const void*)nullptr, 0, 128,
            Wp_t, 128, bp, h8, 768, CM, 128, 6);

        gather6<<<(CM + 1) / 2, 256, 0, stream>>>(h8, rec, off + rows0, agg8, CM);

        // proj = relu([Hbk|agg8] @ Wfull + bcomb)  [CM,384]; proj aliases h8
        mgemm<0, true, true><<<3 * MB, 256, 0, stream>>>(
            Hbk, 128, agg8, 768, 128,
            Wfull_t, 896, bcomb, proj, 384, CM, 896, 3);

        // xs_chunk = [Hbk|proj] @ Wpl + bpl   [CM,128]
        mgemm<0, false, false><<<1 * MB, 256, 0, stream>>>(
            Hbk, 128, proj, 384, 128,
            Wpl_t, 512, bpl, xs + (size_t)rows0 * 128, 128, CM, 512, 1);
    }

    // ---- fused LSTM ----
    lstm_fused<<<(NN + 31) / 32, 512, 0, stream>>>(xs, WihWhh_t, bias_lstm,
                                                   (float*)d_out);
}

// Round 21
// 687.046 us; speedup vs baseline: 1.0116x; 1.0116x over previous
//
#include <hip/hip_runtime.h>
#include <math.h>

constexpr int NN  = 30000;
constexpr int DIM = 128;
constexpr int KH  = 3;
constexpr int NC  = 6;
constexpr int EE  = 480000;
constexpr int NBLK3 = (3 * NN + 255) / 256;   // 352 scan blocks (batched)

typedef __attribute__((ext_vector_type(8))) short short8;
typedef __attribute__((ext_vector_type(4))) float f32x4;
typedef __attribute__((ext_vector_type(2))) float f32x2;

__device__ __forceinline__ unsigned short f2bf(float f) {
    union { float f; unsigned int i; } c; c.f = f;
    unsigned int u = c.i;
    return (unsigned short)((u + 0x7fffu + ((u >> 16) & 1u)) >> 16);
}
__device__ __forceinline__ float bf2f(unsigned int u) {
    union { unsigned int i; float f; } c; c.i = u << 16; return c.f;
}
__device__ __forceinline__ unsigned int packbf(float x, float y) {
    return (unsigned int)f2bf(x) | ((unsigned int)f2bf(y) << 16);
}
__device__ __forceinline__ float fsig(float x) {
    return __builtin_amdgcn_rcpf(1.f + __expf(-x));
}
__device__ __forceinline__ float ftanh(float x) {
    return 2.f * fsig(2.f * x) - 1.f;
}
// 4 fp8 (one u32) -> 2 u32 of bf16 pairs
__device__ __forceinline__ void fp8x4_to_bf16x4(unsigned int x,
                                                unsigned int& o0, unsigned int& o1)
{
    f32x2 lo = __builtin_amdgcn_cvt_pk_f32_fp8(x, false);
    f32x2 hi = __builtin_amdgcn_cvt_pk_f32_fp8(x, true);
    o0 = packbf(lo.x, lo.y);
    o1 = packbf(hi.x, hi.y);
}

// ---------------------------------------------------------------------------
// bf16 MFMA GEMM (reg-staged). A split at ksplit (A1 bf16 / A2 bf16-or-fp8).
// A2FP8: A2 is fp8 e4m3 (lda2 in BYTES per row); converted to bf16 at staging.
// OUT: 0 = bf16 C, 1 = fp8 C. XCD-chunked bijective swizzle.
// ---------------------------------------------------------------------------
template<int OUT, bool RELU, bool A2FP8>
__global__ __launch_bounds__(256) void mgemm(
    const unsigned short* __restrict__ A1, int lda1,
    const void* __restrict__ A2, int lda2, int ksplit,
    const unsigned short* __restrict__ Bt, int ldb,
    const float* __restrict__ bias,
    void* __restrict__ Cv, int ldc,
    int M, int K, int nx)
{
    __shared__ __align__(16) unsigned char smem[2 * 128 * 80];
    unsigned char* As = smem;
    unsigned char* Bs = smem + 128 * 80;

    const int nwg  = gridDim.x;
    const int orig = blockIdx.x;
    const int q = nwg >> 3, r = nwg & 7;
    const int xcd = orig & 7, idx = orig >> 3;
    const int lin = (xcd < r ? xcd * (q + 1) : r * (q + 1) + (xcd - r) * q) + idx;
    const int bx = lin % nx, by = lin / nx;

    const int tid  = threadIdx.x;
    const int lane = tid & 63;
    const int w    = tid >> 6;
    const int wm   = w >> 1, wn = w & 1;
    const int lm   = lane & 15, lg = lane >> 4;
    const int bm   = by * 128;
    const int bn   = bx * 128;

    const int srow  = tid >> 1;
    const int shalf = tid & 1;

    f32x4 acc[4][4] = {};

    int arow = bm + srow; if (arow > M - 1) arow = M - 1;
    const int brow = bn + srow;

    for (int k0 = 0; k0 < K; k0 += 32) {
        float4 a0, a1;
        if (k0 < ksplit) {
            const float4* ga = (const float4*)(A1 + (size_t)arow * lda1 + k0 + shalf * 16);
            a0 = ga[0]; a1 = ga[1];
        } else if (!A2FP8) {
            const unsigned short* Ap = (const unsigned short*)A2;
            const float4* ga = (const float4*)(Ap + (size_t)arow * lda2 + (k0 - ksplit) + shalf * 16);
            a0 = ga[0]; a1 = ga[1];
        } else {
            const unsigned char* gp = (const unsigned char*)A2 +
                (size_t)arow * lda2 + (k0 - ksplit) + shalf * 16;
            uint4 v = *(const uint4*)gp;
            unsigned int o[8];
            fp8x4_to_bf16x4(v.x, o[0], o[1]);
            fp8x4_to_bf16x4(v.y, o[2], o[3]);
            fp8x4_to_bf16x4(v.z, o[4], o[5]);
            fp8x4_to_bf16x4(v.w, o[6], o[7]);
            a0 = *(float4*)&o[0];
            a1 = *(float4*)&o[4];
        }
        const float4* gb = (const float4*)(Bt + (size_t)brow * ldb + k0 + shalf * 16);
        float4 b0 = gb[0], b1 = gb[1];

        __syncthreads();
        *(float4*)(As + srow * 80 + shalf * 32)      = a0;
        *(float4*)(As + srow * 80 + shalf * 32 + 16) = a1;
        *(float4*)(Bs + srow * 80 + shalf * 32)      = b0;
        *(float4*)(Bs + srow * 80 + shalf * 32 + 16) = b1;
        __syncthreads();

        short8 av[4], bv[4];
        #pragma unroll
        for (int f = 0; f < 4; ++f) {
            av[f] = *(const short8*)(As + (wm * 64 + f * 16 + lm) * 80 + lg * 16);
            bv[f] = *(const short8*)(Bs + (wn * 64 + f * 16 + lm) * 80 + lg * 16);
        }
        #pragma unroll
        for (int i = 0; i < 4; ++i)
            #pragma unroll
            for (int j = 0; j < 4; ++j)
                acc[i][j] = __builtin_amdgcn_mfma_f32_16x16x32_bf16(
                    av[i], bv[j], acc[i][j], 0, 0, 0);
    }

    #pragma unroll
    for (int i = 0; i < 4; ++i) {
        int row0 = bm + wm * 64 + i * 16 + lg * 4;
        #pragma unroll
        for (int j = 0; j < 4; ++j) {
            int col = bn + wn * 64 + j * 16 + lm;
            float bb = bias[col];
            #pragma unroll
            for (int r2 = 0; r2 < 4; ++r2) {
                int row = row0 + r2;
                if (row < M) {
                    float v = acc[i][j][r2] + bb;
                    if (RELU) v = fmaxf(v, 0.f);
                    if (OUT == 0) {
                        ((unsigned short*)Cv)[(size_t)row * ldc + col] = f2bf(v);
                    } else {
                        unsigned int pk = __builtin_amdgcn_cvt_pk_fp8_f32(v, v, 0, false);
                        ((unsigned char*)Cv)[(size_t)row * ldc + col] = (unsigned char)pk;
                    }
                }
            }
        }
    }
}

// ---------------------------------------------------------------------------
// Batched CSR build; edge record = 16B {src, 6 bf16 w}; off values GLOBAL.
// ---------------------------------------------------------------------------
__global__ void hist3(const int* __restrict__ EL, int* __restrict__ cnt)
{
    int t = blockIdx.x * 256 + threadIdx.x;
    int e0 = t * 4;
    if (e0 >= 3 * EE) return;
    int g = e0 / EE;
    int e = e0 - g * EE;
    int4 d4 = *(const int4*)(EL + (size_t)g * 2 * EE + EE + e);
    int* c = cnt + g * NN;
    atomicAdd(&c[d4.x], 1);
    atomicAdd(&c[d4.y], 1);
    atomicAdd(&c[d4.z], 1);
    atomicAdd(&c[d4.w], 1);
}

__global__ __launch_bounds__(256) void scan_part(const int* __restrict__ cnt,
                                                 int* __restrict__ off,
                                                 int* __restrict__ bsum, int n)
{
    int lane = threadIdx.x & 63, wid = threadIdx.x >> 6;
    int i = blockIdx.x * 256 + threadIdx.x;
    int v = (i < n) ? cnt[i] : 0;
    int x = v;
    #pragma unroll
    for (int ofs = 1; ofs < 64; ofs <<= 1) {
        int t = __shfl_up(x, ofs, 64);
        if (lane >= ofs) x += t;
    }
    __shared__ int ws[4];
    if (lane == 63) ws[wid] = x;
    __syncthreads();
    int wo = 0;
    for (int j = 0; j < wid; ++j) wo += ws[j];
    if (i < n) off[i] = wo + x - v;
    if (threadIdx.x == 255) bsum[blockIdx.x] = wo + x;
}

__global__ __launch_bounds__(512) void scan_tops(const int* __restrict__ bsum,
                                                 int* __restrict__ btop, int nb)
{
    __shared__ int buf[512];
    int v = (threadIdx.x < nb) ? bsum[threadIdx.x] : 0;
    buf[threadIdx.x] = v;
    __syncthreads();
    #pragma unroll
    for (int ofs = 1; ofs < 512; ofs <<= 1) {
        int t = (threadIdx.x >= ofs) ? buf[threadIdx.x - ofs] : 0;
        __syncthreads();
        buf[threadIdx.x] += t;
        __syncthreads();
    }
    if (threadIdx.x < nb) btop[threadIdx.x] = buf[threadIdx.x] - v;
}

__global__ __launch_bounds__(256) void scan_add(int* __restrict__ off,
                                                const int* __restrict__ btop,
                                                int* __restrict__ cursor,
                                                int n, int etot)
{
    int i = blockIdx.x * 256 + threadIdx.x;
    if (i < n) {
        int o = off[i] + btop[blockIdx.x];
        off[i] = o;
        cursor[i] = o;
    }
    if (blockIdx.x == 0 && threadIdx.x == 0) off[n] = etot;
}

__global__ void fill3(const int* __restrict__ EL, const float* __restrict__ SW,
                      int* __restrict__ cursor, uint4* __restrict__ rec)
{
    int t = blockIdx.x * 256 + threadIdx.x;
    int e0 = t * 4;
    if (e0 >= 3 * EE) return;
    int g = e0 / EE;
    int e = e0 - g * EE;
    const int* base = EL + (size_t)g * 2 * EE;
    int4 s4 = *(const int4*)(base + e);
    int4 d4 = *(const int4*)(base + EE + e);
    const float* sw = SW + (size_t)g * NC * EE;
    float4 w0 = *(const float4*)(sw + e);
    float4 w1 = *(const float4*)(sw + (size_t)EE + e);
    float4 w2 = *(const float4*)(sw + 2 * (size_t)EE + e);
    float4 w3 = *(const float4*)(sw + 3 * (size_t)EE + e);
    float4 w4 = *(const float4*)(sw + 4 * (size_t)EE + e);
    float4 w5 = *(const float4*)(sw + 5 * (size_t)EE + e);
    int* cur = cursor + g * NN;
    int p0 = atomicAdd(&cur[d4.x], 1);
    int p1 = atomicAdd(&cur[d4.y], 1);
    int p2 = atomicAdd(&cur[d4.z], 1);
    int p3 = atomicAdd(&cur[d4.w], 1);
    rec[p0] = make_uint4((unsigned)s4.x, packbf(w0.x, w1.x), packbf(w2.x, w3.x), packbf(w4.x, w5.x));
    rec[p1] = make_uint4((unsigned)s4.y, packbf(w0.y, w1.y), packbf(w2.y, w3.y), packbf(w4.y, w5.y));
    rec[p2] = make_uint4((unsigned)s4.z, packbf(w0.z, w1.z), packbf(w2.z, w3.z), packbf(w4.z, w5.z));
    rec[p3] = make_uint4((unsigned)s4.w, packbf(w0.w, w1.w), packbf(w2.w, w3.w), packbf(w4.w, w5.w));
}

// ---------------------------------------------------------------------------
// Fused 6-conv weighted segment-mean gather over 16B edge records.
// 2 waves/node, unroll-4 pipeline (fastest measured). agg fp8 [*,768].
// ---------------------------------------------------------------------------
__device__ __forceinline__ void wunpack(uint4 r, int half,
                                        float& w0, float& w1, float& w2)
{
    if (half == 0) {
        w0 = bf2f(r.y & 0xffffu); w1 = bf2f(r.y >> 16); w2 = bf2f(r.z & 0xffffu);
    } else {
        w0 = bf2f(r.z >> 16); w1 = bf2f(r.w & 0xffffu); w2 = bf2f(r.w >> 16);
    }
}

__global__ __launch_bounds__(256) void gather6(
    const unsigned char* __restrict__ h8,
    const uint4* __restrict__ rec,
    const int* __restrict__ off,
    unsigned char* __restrict__ agg,        // fp8 [*,768]
    int nnodes)
{
    int wid  = threadIdx.x >> 6;
    int lane = threadIdx.x & 63;
    int node = blockIdx.x * 2 + (wid >> 1);
    int half = wid & 1;
    if (node >= nnodes) return;
    int rowbase = (node / NN) * NN;
    int s0 = off[node], s1 = off[node + 1];
    float a0 = 0.f, a1 = 0.f, b0 = 0.f, b1 = 0.f, c0 = 0.f, c1 = 0.f;
    const size_t hofs = (size_t)half * 384 + (size_t)lane * 2;
    const unsigned char* hb = h8 + (size_t)rowbase * 768 + hofs;

    int e = s0;
    for (; e + 3 < s1; e += 4) {
        uint4 rA = rec[e], rB = rec[e + 1], rC = rec[e + 2], rD = rec[e + 3];
        const unsigned short* pA = (const unsigned short*)(hb + (size_t)rA.x * 768);
        const unsigned short* pB = (const unsigned short*)(hb + (size_t)rB.x * 768);
        const unsigned short* pC = (const unsigned short*)(hb + (size_t)rC.x * 768);
        const unsigned short* pD = (const unsigned short*)(hb + (size_t)rD.x * 768);
        unsigned int pA0 = pA[0], pA1 = pA[64], pA2 = pA[128];
        unsigned int pB0 = pB[0], pB1 = pB[64], pB2 = pB[128];
        unsigned int pC0 = pC[0], pC1 = pC[64], pC2 = pC[128];
        unsigned int pD0 = pD[0], pD1 = pD[64], pD2 = pD[128];

        float w0, w1, w2;
        wunpack(rA, half, w0, w1, w2);
        {
            f32x2 h0 = __builtin_amdgcn_cvt_pk_f32_fp8(pA0, false);
            f32x2 h1 = __builtin_amdgcn_cvt_pk_f32_fp8(pA1, false);
            f32x2 h2 = __builtin_amdgcn_cvt_pk_f32_fp8(pA2, false);
            a0 += w0 * h0.x; a1 += w0 * h0.y;
            b0 += w1 * h1.x; b1 += w1 * h1.y;
            c0 += w2 * h2.x; c1 += w2 * h2.y;
        }
        wunpack(rB, half, w0, w1, w2);
        {
            f32x2 h0 = __builtin_amdgcn_cvt_pk_f32_fp8(pB0, false);
            f32x2 h1 = __builtin_amdgcn_cvt_pk_f32_fp8(pB1, false);
            f32x2 h2 = __builtin_amdgcn_cvt_pk_f32_fp8(pB2, false);
            a0 += w0 * h0.x; a1 += w0 * h0.y;
            b0 += w1 * h1.x; b1 += w1 * h1.y;
            c0 += w2 * h2.x; c1 += w2 * h2.y;
        }
        wunpack(rC, half, w0, w1, w2);
        {
            f32x2 h0 = __builtin_amdgcn_cvt_pk_f32_fp8(pC0, false);
            f32x2 h1 = __builtin_amdgcn_cvt_pk_f32_fp8(pC1, false);
            f32x2 h2 = __builtin_amdgcn_cvt_pk_f32_fp8(pC2, false);
            a0 += w0 * h0.x; a1 += w0 * h0.y;
            b0 += w1 * h1.x; b1 += w1 * h1.y;
            c0 += w2 * h2.x; c1 += w2 * h2.y;
        }
        wunpack(rD, half, w0, w1, w2);
        {
            f32x2 h0 = __builtin_amdgcn_cvt_pk_f32_fp8(pD0, false);
            f32x2 h1 = __builtin_amdgcn_cvt_pk_f32_fp8(pD1, false);
            f32x2 h2 = __builtin_amdgcn_cvt_pk_f32_fp8(pD2, false);
            a0 += w0 * h0.x; a1 += w0 * h0.y;
            b0 += w1 * h1.x; b1 += w1 * h1.y;
            c0 += w2 * h2.x; c1 += w2 * h2.y;
        }
    }
    for (; e < s1; ++e) {
        uint4 r = rec[e];
        float w0, w1, w2;
        wunpack(r, half, w0, w1, w2);
        const unsigned short* hrow = (const unsigned short*)(hb + (size_t)r.x * 768);
        unsigned int q0 = hrow[0];
        unsigned int q1 = hrow[64];
        unsigned int q2 = hrow[128];
        f32x2 h0 = __builtin_amdgcn_cvt_pk_f32_fp8(q0, false);
        f32x2 h1 = __builtin_amdgcn_cvt_pk_f32_fp8(q1, false);
        f32x2 h2 = __builtin_amdgcn_cvt_pk_f32_fp8(q2, false);
        a0 += w0 * h0.x; a1 += w0 * h0.y;
        b0 += w1 * h1.x; b1 += w1 * h1.y;
        c0 += w2 * h2.x; c1 += w2 * h2.y;
    }
    float inv = 1.f / fmaxf((float)(s1 - s0), 1.f);
    unsigned short* orow = (unsigned short*)(agg + (size_t)node * 768) + 192 * half + lane;
    orow[0]   = (unsigned short)__builtin_amdgcn_cvt_pk_fp8_f32(a0 * inv, a1 * inv, 0, false);
    orow[64]  = (unsigned short)__builtin_amdgcn_cvt_pk_fp8_f32(b0 * inv, b1 * inv, 0, false);
    orow[128] = (unsigned short)__builtin_amdgcn_cvt_pk_fp8_f32(c0 * inv, c1 * inv, 0, false);
}

// ---------------------------------------------------------------------------
__global__ void cvt_h(const float* __restrict__ Hk, unsigned int* __restrict__ out,
                      int total)
{
    int idx = blockIdx.x * 256 + threadIdx.x;
    if (idx >= total) return;
    float2 v = ((const float2*)Hk)[idx];
    out[idx] = packbf(v.x, v.y);
}

// ---------------------------------------------------------------------------
// Fused 3-step LSTM (weights hoisted to registers; unchanged).
// ---------------------------------------------------------------------------
#define SWA32(r, b) ((r) * 512 + ((b) ^ (((r) & 7) << 4)))

__global__ __launch_bounds__(512) void lstm_fused(
    const unsigned short* __restrict__ xs,   // [3][NN][128]
    const unsigned short* __restrict__ Wt,   // [512][256] permuted rows
    const float* __restrict__ bsum,          // [512] permuted
    float* __restrict__ outp)                // [NN][128]
{
    __shared__ __align__(16) unsigned char AL[32 * 512];

    const int tid  = threadIdx.x;
    const int lane = tid & 63;
    const int w    = tid >> 6;              // 0..7
    const int lm   = lane & 15, lg = lane >> 4;
    const int node0 = blockIdx.x * 32;

    float bias[4];
    #pragma unroll
    for (int g = 0; g < 4; ++g)
        bias[g] = bsum[w * 64 + g * 16 + lm];

    short8 bw[8][4];
    #pragma unroll
    for (int ks = 0; ks < 8; ++ks)
        #pragma unroll
        for (int g = 0; g < 4; ++g)
            bw[ks][g] = *(const short8*)(Wt +
                (size_t)(w * 64 + g * 16 + lm) * 256 + ks * 32 + lg * 8);

    float cst[2][4] = {};

    float4 z4 = make_float4(0.f, 0.f, 0.f, 0.f);
    {
        int r = tid >> 4, gi = tid & 15;
        *(float4*)(AL + SWA32(r, 256 + gi * 16)) = z4;
    }

    for (int t = 0; t < KH; ++t) {
        const unsigned short* xsrc = xs + (size_t)t * NN * 128;
        {
            int r = tid >> 4, gi = tid & 15;
            int gr = node0 + r; if (gr >= NN) gr = NN - 1;
            float4 v = *(const float4*)(xsrc + (size_t)gr * 128 + gi * 8);
            *(float4*)(AL + SWA32(r, gi * 16)) = v;
        }
        __syncthreads();

        f32x4 acc[2][4] = {};
        #pragma unroll
        for (int ks = 0; ks < 8; ++ks) {
            short8 av[2];
            #pragma unroll
            for (int i = 0; i < 2; ++i)
                av[i] = *(const short8*)(AL + SWA32(i * 16 + lm, ks * 64 + lg * 16));
            #pragma unroll
            for (int g = 0; g < 4; ++g)
                #pragma unroll
                for (int i = 0; i < 2; ++i)
                    acc[i][g] = __builtin_amdgcn_mfma_f32_16x16x32_bf16(
                        av[i], bw[ks][g], acc[i][g], 0, 0, 0);
        }
        __syncthreads();

        #pragma unroll
        for (int i = 0; i < 2; ++i)
            #pragma unroll
            for (int r = 0; r < 4; ++r) {
                float giv = acc[i][0][r] + bias[0];
                float gfv = acc[i][1][r] + bias[1];
                float ggv = acc[i][2][r] + bias[2];
                float gov = acc[i][3][r] + bias[3];
                float si = fsig(giv);
                float sf = fsig(gfv);
                float so = fsig(gov);
                float cv = sf * cst[i][r] + si * ftanh(ggv);
                cst[i][r] = cv;
                float hv = so * ftanh(cv);
                int row = i * 16 + lg * 4 + r;
                int d   = w * 16 + lm;
                if (t < KH - 1) {
                    *(unsigned short*)(AL + SWA32(row, 256 + 2 * d)) = f2bf(hv);
                } else if (node0 + row < NN) {
                    outp[(size_t)(node0 + row) * 128 + d] = fmaxf(hv, 0.f);
                }
            }
    }
}

// ---------------------------------------------------------------------------
// Weight precompute: tiled fp32 GEMM fold (unchanged).
// ---------------------------------------------------------------------------
__global__ __launch_bounds__(256) void wt_fold(
    const float* __restrict__ Wcomb,
    const float* __restrict__ Wroot,
    const float* __restrict__ Wrel,
    unsigned short* __restrict__ Wfull_t)
{
    __shared__ __align__(16) float As[16][68];
    __shared__ __align__(16) float Bs[16][68];
    const int tid = threadIdx.x;
    const int tx = tid & 15, ty = tid >> 4;
    const int bm = blockIdx.y * 64;
    const int bn = blockIdx.x * 64;
    const bool root = (bm < 128);
    const int i0 = root ? 0 : (bm >> 7) - 1;
    const int i1 = root ? NC : i0 + 1;
    const int mloc = bm & 127;
    const int a_m = tid >> 2, a_k = (tid & 3) * 4;
    const int b_k = tid >> 4, b_n = (tid & 15) * 4;

    float acc[4][4] = {};

    for (int i = i0; i < i1; ++i) {
        const float* A = (root ? Wroot : Wrel) + (size_t)i * 128 * 128;
        const float* B = Wcomb + (size_t)(i + 1) * 128 * 384;
        for (int k0 = 0; k0 < 128; k0 += 16) {
            float4 va = *(const float4*)(A + (size_t)(mloc + a_m) * 128 + k0 + a_k);
            float4 vb = *(const float4*)(B + (size_t)(k0 + b_k) * 384 + bn + b_n);
            __syncthreads();
            As[a_k + 0][a_m] = va.x; As[a_k + 1][a_m] = va.y;
            As[a_k + 2][a_m] = va.z; As[a_k + 3][a_m] = va.w;
            *(float4*)&Bs[b_k][b_n] = vb;
            __syncthreads();
            #pragma unroll
            for (int kk = 0; kk < 16; ++kk) {
                float4 av = *(const float4*)&As[kk][ty * 4];
                float4 bv = *(const float4*)&Bs[kk][tx * 4];
                float a[4] = {av.x, av.y, av.z, av.w};
                float b[4] = {bv.x, bv.y, bv.z, bv.w};
                #pragma unroll
                for (int ii = 0; ii < 4; ++ii)
                    #pragma unroll
                    for (int j = 0; j < 4; ++j)
                        acc[ii][j] += a[ii] * b[j];
            }
        }
    }

    #pragma unroll
    for (int ii = 0; ii < 4; ++ii) {
        int m = bm + ty * 4 + ii;
        #pragma unroll
        for (int j = 0; j < 4; ++j) {
            int n = bn + tx * 4 + j;
            float v = acc[ii][j];
            if (root) v += Wcomb[(size_t)m * 384 + n];
            Wfull_t[(size_t)n * 896 + m] = f2bf(v);
        }
    }
}

// ---------------------------------------------------------------------------
__global__ __launch_bounds__(256) void tr_cvt(
    const float* __restrict__ src, unsigned short* __restrict__ dst,
    int R, int C)
{
    __shared__ float s[32][33];
    const float* sb = src + (size_t)blockIdx.z * R * C;
    unsigned short* db = dst + (size_t)blockIdx.z * R * C;
    int r0 = blockIdx.y * 32, c0 = blockIdx.x * 32;
    int tx = threadIdx.x & 31, ty = threadIdx.x >> 5;   // 32x8
    #pragma unroll
    for (int q = 0; q < 4; ++q)
        s[ty + q * 8][tx] = sb[(size_t)(r0 + ty + q * 8) * C + c0 + tx];
    __syncthreads();
    #pragma unroll
    for (int q = 0; q < 4; ++q)
        db[(size_t)(c0 + ty + q * 8) * R + r0 + tx] = f2bf(s[tx][ty + q * 8]);
}

__global__ void wt_lstm(const float* __restrict__ Wih, const float* __restrict__ Whh,
                        const float* __restrict__ bih, const float* __restrict__ bhh,
                        unsigned short* __restrict__ Wt, float* __restrict__ bsum)
{
    int idx = blockIdx.x * 256 + threadIdx.x;
    if (idx < 512) {
        int w = idx >> 6, rem = idx & 63, g = rem >> 4, d16 = rem & 15;
        int n = g * 128 + w * 16 + d16;
        bsum[idx] = bih[n] + bhh[n];
    }
    if (idx >= 512 * 256) return;
    int k = idx & 255, np = idx >> 8;
    int w = np >> 6, rem = np & 63, g = rem >> 4, d16 = rem & 15;
    int n = g * 128 + w * 16 + d16;
    Wt[idx] = f2bf(k < 128 ? Wih[(size_t)n * DIM + k]
                           : Whh[(size_t)n * DIM + (k - 128)]);
}

// ---------------------------------------------------------------------------
extern "C" void kernel_launch(void* const* d_in, const int* in_sizes, int n_in,
                              void* d_out, int out_size, void* d_ws, size_t ws_size,
                              hipStream_t stream)
{
    const float* H     = (const float*)d_in[0];
    const int*   EL    = (const int*)  d_in[1];
    const float* SW    = (const float*)d_in[2];
    const float* Wp    = (const float*)d_in[3];
    const float* bp    = (const float*)d_in[4];
    const float* Wrel  = (const float*)d_in[5];
    const float* Wroot = (const float*)d_in[6];
    const float* Wcomb = (const float*)d_in[7];
    const float* bcomb = (const float*)d_in[8];
    const float* Wpl   = (const float*)d_in[9];
    const float* bpl   = (const float*)d_in[10];
    const float* Wih   = (const float*)d_in[11];
    const float* Whh   = (const float*)d_in[12];
    const float* bih   = (const float*)d_in[13];
    const float* bhh   = (const float*)d_in[14];

    char* wp = (char*)d_ws;
    auto alloc = [&](size_t b) {
        char* p = wp; wp += (b + 255) & ~(size_t)255; return p;
    };

    // common allocations (~71 MB)
    unsigned short* Hbf  = (unsigned short*)alloc((size_t)3 * NN * 128 * 2);
    unsigned short* xs   = (unsigned short*)alloc((size_t)KH * NN * 128 * 2);
    uint4* rec   = (uint4*)alloc((size_t)3 * EE * 16);
    int* cnt     = (int*)alloc((size_t)3 * NN * 4);
    int* off     = (int*)alloc((size_t)(3 * NN + 1) * 4);
    int* cursor  = (int*)alloc((size_t)3 * NN * 4);
    int* bsum    = (int*)alloc((size_t)NBLK3 * 4);
    int* btop    = (int*)alloc((size_t)NBLK3 * 4);
    unsigned short* Wp_t     = (unsigned short*)alloc((size_t)768 * 128 * 2);
    unsigned short* Wfull_t  = (unsigned short*)alloc((size_t)384 * 896 * 2);
    unsigned short* Wpl_t    = (unsigned short*)alloc((size_t)128 * 512 * 2);
    unsigned short* WihWhh_t = (unsigned short*)alloc((size_t)512 * 256 * 2);
    float* bias_lstm         = (float*)alloc(512 * 4);

    // chunked buffers: proj ALIASES h8 (identical byte size; hazard-free).
    size_t used = (size_t)(wp - (char*)d_ws);
    size_t per_graph = (size_t)NN * 768 * 2 + 1024;
    const int nb = (ws_size - used >= 3 * per_graph + 4096) ? 1 : 3;  // 1 => batched
    const int GM = (nb == 1) ? 3 : 1;
    unsigned char*  h8   = (unsigned char*) alloc((size_t)GM * NN * 768);
    unsigned char*  agg8 = (unsigned char*) alloc((size_t)GM * NN * 768);
    unsigned short* proj = (unsigned short*)h8;   // alias (GM*NN*384*2 == GM*NN*768)

    // ---- weight precompute ----
    tr_cvt<<<dim3(4, 4, 6), 256, 0, stream>>>(Wp, Wp_t, 128, 128);
    wt_fold<<<dim3(6, 14), 256, 0, stream>>>(Wcomb, Wroot, Wrel, Wfull_t);
    tr_cvt<<<dim3(4, 16, 1), 256, 0, stream>>>(Wpl, Wpl_t, 512, 128);
    wt_lstm<<<(512 * 256 + 255) / 256, 256, 0, stream>>>(Wih, Whh, bih, bhh,
                                                         WihWhh_t, bias_lstm);

    // ---- batched CSR build (ILP-4 direct scatter) ----
    hipMemsetAsync(cnt, 0, (size_t)3 * NN * 4, stream);
    hist3<<<(3 * EE / 4 + 255) / 256, 256, 0, stream>>>(EL, cnt);
    scan_part<<<NBLK3, 256, 0, stream>>>(cnt, off, bsum, 3 * NN);
    scan_tops<<<1, 512, 0, stream>>>(bsum, btop, NBLK3);
    scan_add<<<NBLK3, 256, 0, stream>>>(off, btop, cursor, 3 * NN, 3 * EE);
    fill3<<<(3 * EE / 4 + 255) / 256, 256, 0, stream>>>(EL, SW, cursor, rec);

    // ---- batched fp32->bf16 convert of all H ----
    cvt_h<<<(3 * NN * 64 + 255) / 256, 256, 0, stream>>>(H, (unsigned int*)Hbf,
                                                         3 * NN * 64);

    const int CM = GM * NN;
    const int MB = (CM + 127) / 128;

    for (int c = 0; c < nb; ++c) {
        const int rows0 = c * NN;
        const unsigned short* Hbk = Hbf + (size_t)rows0 * 128;

        // h8 = fp8(relu(Hbk @ Wp_all + bp))   [CM,768]
        mgemm<1, true, false><<<6 * MB, 256, 0, stream>>>(
            Hbk, 128, (const void*)nullptr, 0, 128,
            Wp_t, 128, bp, h8, 768, CM, 128, 6);

        gather6<<<(CM + 1) / 2, 256, 0, stream>>>(h8, rec, off + rows0, agg8, CM);

        // proj = relu([Hbk|agg8] @ Wfull + bcomb)  [CM,384]; proj aliases h8
        mgemm<0, true, true><<<3 * MB, 256, 0, stream>>>(
            Hbk, 128, agg8, 768, 128,
            Wfull_t, 896, bcomb, proj, 384, CM, 896, 3);

        // xs_chunk = [Hbk|proj] @ Wpl + bpl   [CM,128]
        mgemm<0, false, false><<<1 * MB, 256, 0, stream>>>(
            Hbk, 128, proj, 384, 128,
            Wpl_t, 512, bpl, xs + (size_t)rows0 * 128, 128, CM, 512, 1);
    }

    // ---- fused LSTM ----
    lstm_fused<<<(NN + 31) / 32, 512, 0, stream>>>(xs, WihWhh_t, bias_lstm,
                                                   (float*)d_out);
}